// Round 9
// baseline (397.976 us; speedup 1.0000x reference)
//
#include <hip/hip_runtime.h>

#define N_NODES 50000
#define N_EDGES 1600000
#define N_CAND  131072
#define D 128
#define ROWS 50176   // padded row count
#define NB 196       // coarse buckets (dst>>8)
#define BCAP 10240   // fixed per-bucket capacity (E[cnt]=8192, sigma~90)
#define LSTR 132     // LDS row stride (bf16 elems)

typedef __attribute__((ext_vector_type(8))) short short8;
typedef __attribute__((ext_vector_type(4))) float f32x4;

__device__ inline short f2bf(float f) {
  unsigned u = __builtin_bit_cast(unsigned, f);
  u = (u + 0x7FFFu + ((u >> 16) & 1u)) >> 16;
  return (short)u;
}
__device__ inline float bf_lo(unsigned u) { return __builtin_bit_cast(float, u << 16); }
__device__ inline float bf_hi(unsigned u) { return __builtin_bit_cast(float, u & 0xFFFF0000u); }
__device__ inline float bfu(unsigned short h) { return __builtin_bit_cast(float, (unsigned)h << 16); }

// direct global->LDS DMA: 64 lanes x 4B = one 256B row per instruction, no VGPR dest
__device__ inline void row_to_lds(const void* g, void* l) {
  __builtin_amdgcn_global_load_lds((__attribute__((address_space(1))) void*)g,
                                   (__attribute__((address_space(3))) void*)l, 4, 0, 0);
}

// ---------------- prep + pass1 merged ----------------
// blocks 0..63: weight frag images; 64..3188: x fp32->bf16; 3189..3579: edge bucketing
// pass1 stages pairs in LDS sorted by bucket, then flushes contiguous runs (write-combining)

__global__ __launch_bounds__(256) void prep_pass1(const float* __restrict__ gw1,
                                                  const float* __restrict__ gw2,
                                                  const float* __restrict__ pw1,
                                                  short* __restrict__ Wf,
                                                  const float* __restrict__ x,
                                                  unsigned short* __restrict__ y,
                                                  const int* __restrict__ src,
                                                  const int* __restrict__ dst,
                                                  int* __restrict__ bucket_cnt,
                                                  int* __restrict__ pairs) {
  int b = blockIdx.x;
  int t = threadIdx.x;
  if (b < 64) {
    int tid = b * 256 + t;  // 0..16383
    int img = tid >> 11, idx = tid & 2047;
    const float* W;
    if (img < 3) W = gw1 + img * 16384;
    else if (img < 6) W = gw2 + (img - 3) * 16384;
    else W = pw1 + (256 + (img - 6) * 128) * 128;
    int n = idx & 127, k8 = idx >> 7;
    short8 s;
#pragma unroll
    for (int j = 0; j < 8; ++j) s[j] = f2bf(W[(k8 * 8 + j) * 128 + n]);
    int kk = k8 >> 2, q = k8 & 3, nt = n >> 4, ln = (n & 15) | (q << 4);
    *(short8*)&Wf[img * 16384 + ((nt * 4 + kk) * 64 + ln) * 8] = s;
  } else if (b < 3189) {
    size_t base = ((size_t)(b - 64) * 256 + t) * 8;
    float4 v0 = *(const float4*)&x[base];
    float4 v1 = *(const float4*)&x[base + 4];
    short8 s;
    s[0] = f2bf(v0.x); s[1] = f2bf(v0.y); s[2] = f2bf(v0.z); s[3] = f2bf(v0.w);
    s[4] = f2bf(v1.x); s[5] = f2bf(v1.y); s[6] = f2bf(v1.z); s[7] = f2bf(v1.w);
    *(short8*)&y[base] = s;
  } else {
    __shared__ int lcnt[NB];
    __shared__ int loff[NB];
    __shared__ int gbase[NB];
    __shared__ int scanbuf[256];
    __shared__ int stage[4096];
    int e0 = (b - 3189) * 4096;
    for (int i = t; i < NB; i += 256) lcnt[i] = 0;
    __syncthreads();
    int d[16], s[16], r[16];
#pragma unroll
    for (int i = 0; i < 16; ++i) {
      int e = e0 + i * 256 + t;
      if (e < N_EDGES) {
        d[i] = dst[e]; s[i] = src[e];
        r[i] = atomicAdd(&lcnt[d[i] >> 8], 1);
      } else d[i] = -1;
    }
    __syncthreads();
    // exclusive scan of lcnt -> loff; reserve global ranges -> gbase
    {
      int v = (t < NB) ? lcnt[t] : 0;
      scanbuf[t] = v;
      __syncthreads();
      for (int off = 1; off < 256; off <<= 1) {
        int add = (t >= off) ? scanbuf[t - off] : 0;
        __syncthreads();
        scanbuf[t] += add;
        __syncthreads();
      }
      if (t < NB) {
        loff[t] = scanbuf[t] - v;
        gbase[t] = v ? atomicAdd(&bucket_cnt[t], v) : 0;
      }
    }
    __syncthreads();
    // scatter into LDS stage (bucket-sorted)
#pragma unroll
    for (int i = 0; i < 16; ++i) {
      if (d[i] >= 0) {
        int bb = d[i] >> 8;
        stage[loff[bb] + r[i]] = (s[i] << 8) | (d[i] & 255);
      }
    }
    __syncthreads();
    // flush contiguous runs per bucket (coalesced)
    int w = t >> 6, lane = t & 63;
    for (int bb = w; bb < NB; bb += 4) {
      int c = lcnt[bb], lo = loff[bb], gb = bb * BCAP + gbase[bb];
      for (int k = lane; k < c; k += 64) pairs[gb + k] = stage[lo + k];
    }
  }
}

// ---------------- pass2: within-bucket counting sort -> csr + per-node (beg,end) ----------------

__global__ __launch_bounds__(256) void build_pass2(const int* __restrict__ pairs,
                                                   const int* __restrict__ bucket_cnt,
                                                   int2* __restrict__ rowBE,
                                                   int* __restrict__ csr) {
  __shared__ int cnt_s[256];
  __shared__ int buf[256];
  __shared__ int ssrc[BCAP];
  int t = threadIdx.x;
  int b = blockIdx.x;
  int cnt = bucket_cnt[b];
  int gbase = b * BCAP;
  const int* pp = pairs + gbase;
  cnt_s[t] = 0;
  __syncthreads();
  for (int i = t; i < cnt; i += 256) atomicAdd(&cnt_s[pp[i] & 255], 1);
  __syncthreads();
  int v = cnt_s[t];
  buf[t] = v;
  __syncthreads();
  for (int off = 1; off < 256; off <<= 1) {
    int add = (t >= off) ? buf[t - off] : 0;
    __syncthreads();
    buf[t] += add;
    __syncthreads();
  }
  int excl = buf[t] - v;
  int node = (b << 8) + t;
  if (node < N_NODES) rowBE[node] = make_int2(gbase + excl, gbase + excl + v);
  cnt_s[t] = excl;
  __syncthreads();
  for (int i = t; i < cnt; i += 256) {
    int p = pp[i];
    int pos = atomicAdd(&cnt_s[p & 255], 1);
    ssrc[pos] = p >> 8;
  }
  __syncthreads();
  for (int i = t; i < cnt; i += 256) csr[gbase + i] = ssrc[i];
}

// ---------------- gather (bf16): out = bf16(x[i] + sum_{j in N(i)} x[j]) ----------------
// global_load_lds DMA: 32 rows truly outstanding per wave (vmcnt queue, no VGPR dests)
// CRITICAL: explicit s_waitcnt vmcnt(0) between DMA issue and LDS consume — the
// compiler does NOT insert it without a barrier (round-8 failure: uninit-LDS reads).

__global__ __launch_bounds__(256) void gather_bf(const unsigned short* __restrict__ x,
                                                 const int2* __restrict__ rowBE,
                                                 const int* __restrict__ csr,
                                                 unsigned short* __restrict__ out, int n) {
  __shared__ unsigned rows[4][32 * 64];   // 4 waves x 32 rows x 256B = 32KB
  int w = __builtin_amdgcn_readfirstlane(threadIdx.x >> 6);
  int lane = threadIdx.x & 63;
  unsigned* hw = rows[w];
  int node = blockIdx.x * 4 + w;
  if (node >= n) return;
  int2 be = rowBE[node];
  const char* xb = (const char*)x;
  int voff = lane * 4;
  unsigned sv = *(const unsigned*)(xb + (size_t)node * 256 + voff);
  float a0 = bf_lo(sv), a1 = bf_hi(sv);
  for (int e = be.x; e < be.y; e += 64) {
    int cnt = min(64, be.y - e);
    int sidx = (e + lane < be.y) ? csr[e + lane] : 0;
    for (int i0 = 0; i0 < cnt; i0 += 32) {
      int bc = min(32, cnt - i0);
      for (int j = 0; j < bc; ++j) {
        int s = __builtin_amdgcn_readlane(sidx, i0 + j);   // SGPR index
        row_to_lds(xb + ((size_t)(unsigned)s << 8) + voff, &hw[j * 64]);
      }
      asm volatile("s_waitcnt vmcnt(0)" ::: "memory");   // drain LDS-DMA before reads
      for (int j = 0; j < bc; ++j) {
        unsigned v = hw[j * 64 + lane];
        a0 += bf_lo(v); a1 += bf_hi(v);
      }
    }
  }
  unsigned r = (unsigned)(unsigned short)f2bf(a0) | ((unsigned)(unsigned short)f2bf(a1) << 16);
  *(unsigned*)&out[(size_t)node * D + lane * 2] = r;
}

// ---------------- fused MLP: Out = relu(A@W1+b1)@W2 + b2 (bf16 in/out) ----------------

__global__ __launch_bounds__(256) void mlp_fused(const unsigned short* __restrict__ A,
                                                 const short* __restrict__ B1f,
                                                 const float* __restrict__ b1,
                                                 const short* __restrict__ B2f,
                                                 const float* __restrict__ b2,
                                                 unsigned short* __restrict__ Out) {
  __shared__ short hbuf[4][32 * LSTR];   // 4 waves x 8448 B
  int t = threadIdx.x;
  int w = t >> 6, lane = t & 63;
  int q = lane >> 4, m = lane & 15;
  int rowBase = blockIdx.x * 128 + w * 32;
  short* hw = hbuf[w];

  f32x4 acc[2][8] = {};
#pragma unroll
  for (int kk = 0; kk < 4; ++kk) {
    short8 a[2], b[8];
#pragma unroll
    for (int mt = 0; mt < 2; ++mt)
      a[mt] = *(const short8*)&A[(size_t)(rowBase + mt * 16 + m) * D + kk * 32 + q * 8];
#pragma unroll
    for (int nt = 0; nt < 8; ++nt)
      b[nt] = *(const short8*)&B1f[((nt * 4 + kk) * 64 + lane) * 8];
#pragma unroll
    for (int mt = 0; mt < 2; ++mt)
#pragma unroll
      for (int nt = 0; nt < 8; ++nt)
        acc[mt][nt] = __builtin_amdgcn_mfma_f32_16x16x32_bf16(a[mt], b[nt], acc[mt][nt], 0, 0, 0);
  }
  {
    float bv[8];
#pragma unroll
    for (int nt = 0; nt < 8; ++nt) bv[nt] = b1[nt * 16 + m];
#pragma unroll
    for (int mt = 0; mt < 2; ++mt)
#pragma unroll
      for (int nt = 0; nt < 8; ++nt)
#pragma unroll
        for (int r = 0; r < 4; ++r) {
          int row = mt * 16 + q * 4 + r, col = nt * 16 + m;
          hw[row * LSTR + col] = f2bf(fmaxf(acc[mt][nt][r] + bv[nt], 0.f));
        }
  }
  f32x4 acc2[2][8] = {};
#pragma unroll
  for (int kk = 0; kk < 4; ++kk) {
    short8 a[2], b[8];
#pragma unroll
    for (int mt = 0; mt < 2; ++mt)
      a[mt] = *(short8*)&hw[(mt * 16 + m) * LSTR + kk * 32 + q * 8];
#pragma unroll
    for (int nt = 0; nt < 8; ++nt)
      b[nt] = *(const short8*)&B2f[((nt * 4 + kk) * 64 + lane) * 8];
#pragma unroll
    for (int mt = 0; mt < 2; ++mt)
#pragma unroll
      for (int nt = 0; nt < 8; ++nt)
        acc2[mt][nt] = __builtin_amdgcn_mfma_f32_16x16x32_bf16(a[mt], b[nt], acc2[mt][nt], 0, 0, 0);
  }
  {
    float bv[8];
#pragma unroll
    for (int nt = 0; nt < 8; ++nt) bv[nt] = b2[nt * 16 + m];
#pragma unroll
    for (int mt = 0; mt < 2; ++mt)
#pragma unroll
      for (int nt = 0; nt < 8; ++nt)
#pragma unroll
        for (int r = 0; r < 4; ++r) {
          int row = mt * 16 + q * 4 + r, col = nt * 16 + m;
          hw[row * LSTR + col] = f2bf(acc2[mt][nt][r] + bv[nt]);
        }
  }
#pragma unroll
  for (int i = 0; i < 8; ++i) {
    int s = i * 64 + lane;
    int row = s >> 4, c8 = s & 15;
    short8 vv = *(short8*)&hw[row * LSTR + c8 * 8];
    int grow = rowBase + row;
    if (grow < N_NODES)
      *(short8*)&Out[(size_t)grow * D + c8 * 8] = vv;
  }
}

// ---------------- target vector: parallel over 4 k-segments ----------------

__global__ __launch_bounds__(512) void tvec_kernel(const unsigned short* __restrict__ x,
                                                   const int* __restrict__ ep,
                                                   const float* __restrict__ W1,
                                                   const float* __restrict__ b1,
                                                   float* __restrict__ tvec) {
  __shared__ float su[128], sv[128];
  __shared__ float part[4][128];
  int t = threadIdx.x;
  int j = t & 127, seg = t >> 7;
  if (t < 128) {
    int u = ep[0], v = ep[1];
    su[j] = bfu(x[(size_t)u * D + j]);
    sv[j] = bfu(x[(size_t)v * D + j]);
  }
  __syncthreads();
  float acc = 0.f;
  int k0 = seg * 32;
#pragma unroll
  for (int k = 0; k < 32; ++k) {
    float s = su[k0 + k] + sv[k0 + k];
    float d = fabsf(su[k0 + k] - sv[k0 + k]);
    acc += s * W1[(k0 + k) * D + j] + d * W1[(128 + k0 + k) * D + j];
  }
  part[seg][j] = acc;
  __syncthreads();
  if (t < 128) tvec[j] = b1[j] + part[0][j] + part[1][j] + part[2][j] + part[3][j];
}

// ---------------- predictor: 256 threads, 128-cand tile ----------------

__global__ __launch_bounds__(256, 4) void pred_kernel(const unsigned short* __restrict__ x,
                                                      const int* __restrict__ cand,
                                                      const short* __restrict__ Wf,
                                                      const float* __restrict__ tvec,
                                                      const float* __restrict__ w2,
                                                      const float* __restrict__ b2,
                                                      float* __restrict__ out) {
  __shared__ short sS[16384];
  __shared__ short sD[16384];
  int t = threadIdx.x;
  int blockRow = blockIdx.x * 128;
  int w = t >> 6, lane = t & 63;

  for (int i = 0; i < 8; ++i) {
    int idx = t + i * 256;
    int m = idx >> 4, j8 = idx & 15;
    int c = blockRow + m;
    int2 uv = ((const int2*)cand)[c];
    short8 su8 = *(const short8*)&x[(size_t)uv.x * D + j8 * 8];
    short8 sv8 = *(const short8*)&x[(size_t)uv.y * D + j8 * 8];
    short8 ss, sd;
#pragma unroll
    for (int j = 0; j < 8; ++j) {
      float uf = bfu((unsigned short)su8[j]);
      float vf = bfu((unsigned short)sv8[j]);
      ss[j] = f2bf(uf + vf);
      sd[j] = f2bf(fabsf(uf - vf));
    }
    int kk = j8 >> 2, qq = j8 & 3, mt = m >> 4, ln = (m & 15) | (qq << 4);
    int slot = ((mt * 4 + kk) * 64 + ln) * 8;
    *(short8*)&sS[slot] = ss;
    *(short8*)&sD[slot] = sd;
  }
  __syncthreads();

  f32x4 acc[2][8] = {};
  const short* B0 = Wf + 6 * 16384;
  const short* B1 = Wf + 7 * 16384;
  for (int kk = 0; kk < 4; ++kk) {
    short8 a0[2], a1[2];
#pragma unroll
    for (int mt = 0; mt < 2; ++mt) {
      a0[mt] = *(short8*)&sS[(((w * 2 + mt) * 4 + kk) * 64 + lane) * 8];
      a1[mt] = *(short8*)&sD[(((w * 2 + mt) * 4 + kk) * 64 + lane) * 8];
    }
#pragma unroll
    for (int nt = 0; nt < 8; ++nt) {
      short8 b0 = *(const short8*)&B0[((nt * 4 + kk) * 64 + lane) * 8];
      short8 b1 = *(const short8*)&B1[((nt * 4 + kk) * 64 + lane) * 8];
#pragma unroll
      for (int mt = 0; mt < 2; ++mt) {
        acc[mt][nt] = __builtin_amdgcn_mfma_f32_16x16x32_bf16(a0[mt], b0, acc[mt][nt], 0, 0, 0);
        acc[mt][nt] = __builtin_amdgcn_mfma_f32_16x16x32_bf16(a1[mt], b1, acc[mt][nt], 0, 0, 0);
      }
    }
  }

  int colbase = lane & 15, rq = lane >> 4;
  float tv[8], w2v[8];
#pragma unroll
  for (int nt = 0; nt < 8; ++nt) {
    tv[nt] = tvec[nt * 16 + colbase];
    w2v[nt] = w2[nt * 16 + colbase];
  }
  float b2v = b2[0];
#pragma unroll
  for (int mt = 0; mt < 2; ++mt) {
    float part[4] = {0.f, 0.f, 0.f, 0.f};
#pragma unroll
    for (int nt = 0; nt < 8; ++nt)
#pragma unroll
      for (int r = 0; r < 4; ++r) {
        float h = acc[mt][nt][r] + tv[nt];
        h = fmaxf(h, 0.f);
        part[r] += h * w2v[nt];
      }
#pragma unroll
    for (int r = 0; r < 4; ++r)
      for (int msk = 1; msk < 16; msk <<= 1)
        part[r] += __shfl_xor(part[r], msk, 64);
    if (colbase == 0) {
      int row0 = blockRow + (w * 2 + mt) * 16 + rq * 4;
#pragma unroll
      for (int r = 0; r < 4; ++r) out[row0 + r] = part[r] + b2v;
    }
  }
}

// ---------------- launch ----------------

extern "C" void kernel_launch(void* const* d_in, const int* in_sizes, int n_in,
                              void* d_out, int out_size, void* d_ws, size_t ws_size,
                              hipStream_t stream) {
  const float* x_in = (const float*)d_in[0];
  const int* edge_index = (const int*)d_in[1];
  const int* ep = (const int*)d_in[2];
  const int* cand = (const int*)d_in[3];
  const float* gw1 = (const float*)d_in[4];
  const float* gb1 = (const float*)d_in[5];
  const float* gw2 = (const float*)d_in[6];
  const float* gb2 = (const float*)d_in[7];
  const float* pw1 = (const float*)d_in[8];
  const float* pb1 = (const float*)d_in[9];
  const float* pw2 = (const float*)d_in[10];
  const float* pb2 = (const float*)d_in[11];
  float* out = (float*)d_out;

  char* ws = (char*)d_ws;
  size_t off = 0;
  auto alloc = [&](size_t bytes) {
    void* p = ws + off;
    off += (bytes + 255) & ~(size_t)255;
    return p;
  };
  unsigned short* xA = (unsigned short*)alloc((size_t)ROWS * D * 2);
  unsigned short* bufA = (unsigned short*)alloc((size_t)ROWS * D * 2);
  unsigned short* xB = (unsigned short*)alloc((size_t)ROWS * D * 2);
  int* pairs       = (int*)alloc((size_t)NB * BCAP * 4);
  int* csr         = (int*)alloc((size_t)NB * BCAP * 4);
  int2* rowBE      = (int2*)alloc((size_t)N_NODES * 8);
  int* bucket_cnt  = (int*)alloc((size_t)NB * 4);
  short* Wf        = (short*)alloc((size_t)8 * 16384 * 2);
  float* tvec      = (float*)alloc(D * 4);

  const int* src = edge_index;
  const int* dst = edge_index + N_EDGES;

  hipMemsetAsync(bucket_cnt, 0, (size_t)NB * 4, stream);
  prep_pass1<<<3580, 256, 0, stream>>>(gw1, gw2, pw1, Wf, x_in, xA, src, dst, bucket_cnt, pairs);
  build_pass2<<<NB, 256, 0, stream>>>(pairs, bucket_cnt, rowBE, csr);

  const int gemm_grid = (N_NODES + 127) / 128;
  gather_bf<<<(N_NODES + 3) / 4, 256, 0, stream>>>(xA, rowBE, csr, bufA, N_NODES);
  mlp_fused<<<gemm_grid, 256, 0, stream>>>(bufA, Wf + 0 * 16384, gb1 + 0 * D,
                                           Wf + 3 * 16384, gb2 + 0 * D, xB);
  gather_bf<<<(N_NODES + 3) / 4, 256, 0, stream>>>(xB, rowBE, csr, bufA, N_NODES);
  mlp_fused<<<gemm_grid, 256, 0, stream>>>(bufA, Wf + 1 * 16384, gb1 + 1 * D,
                                           Wf + 4 * 16384, gb2 + 1 * D, xA);
  gather_bf<<<(N_NODES + 3) / 4, 256, 0, stream>>>(xA, rowBE, csr, bufA, N_NODES);
  mlp_fused<<<gemm_grid, 256, 0, stream>>>(bufA, Wf + 2 * 16384, gb1 + 2 * D,
                                           Wf + 5 * 16384, gb2 + 2 * D, xB);

  tvec_kernel<<<1, 512, 0, stream>>>(xB, ep, pw1, pb1, tvec);
  pred_kernel<<<N_CAND / 128, 256, 0, stream>>>(xB, cand, Wf, tvec, pw2, pb2, out);
}

// Round 10
// 349.518 us; speedup vs baseline: 1.1386x; 1.1386x over previous
//
#include <hip/hip_runtime.h>

#define N_NODES 50000
#define N_EDGES 1600000
#define N_CAND  131072
#define D 128
#define ROWS 50176   // padded row count
#define NB 196       // coarse buckets (dst>>8)
#define BCAP 10240   // fixed per-bucket capacity (E[cnt]=8192, sigma~90)
#define LSTR 132     // LDS row stride (bf16 elems)

typedef __attribute__((ext_vector_type(8))) short short8;
typedef __attribute__((ext_vector_type(4))) float f32x4;

__device__ inline short f2bf(float f) {
  unsigned u = __builtin_bit_cast(unsigned, f);
  u = (u + 0x7FFFu + ((u >> 16) & 1u)) >> 16;
  return (short)u;
}
__device__ inline float bf_lo(unsigned u) { return __builtin_bit_cast(float, u << 16); }
__device__ inline float bf_hi(unsigned u) { return __builtin_bit_cast(float, u & 0xFFFF0000u); }
__device__ inline float bfu(unsigned short h) { return __builtin_bit_cast(float, (unsigned)h << 16); }

// ---------------- prep + pass1 merged ----------------
// blocks 0..63: weight frag images; 64..3188: x fp32->bf16; 3189..3579: edge bucketing
// pass1 stages pairs in LDS sorted by bucket, then flushes contiguous runs (write-combining)

__global__ __launch_bounds__(256) void prep_pass1(const float* __restrict__ gw1,
                                                  const float* __restrict__ gw2,
                                                  const float* __restrict__ pw1,
                                                  short* __restrict__ Wf,
                                                  const float* __restrict__ x,
                                                  unsigned short* __restrict__ y,
                                                  const int* __restrict__ src,
                                                  const int* __restrict__ dst,
                                                  int* __restrict__ bucket_cnt,
                                                  int* __restrict__ pairs) {
  int b = blockIdx.x;
  int t = threadIdx.x;
  if (b < 64) {
    int tid = b * 256 + t;  // 0..16383
    int img = tid >> 11, idx = tid & 2047;
    const float* W;
    if (img < 3) W = gw1 + img * 16384;
    else if (img < 6) W = gw2 + (img - 3) * 16384;
    else W = pw1 + (256 + (img - 6) * 128) * 128;
    int n = idx & 127, k8 = idx >> 7;
    short8 s;
#pragma unroll
    for (int j = 0; j < 8; ++j) s[j] = f2bf(W[(k8 * 8 + j) * 128 + n]);
    int kk = k8 >> 2, q = k8 & 3, nt = n >> 4, ln = (n & 15) | (q << 4);
    *(short8*)&Wf[img * 16384 + ((nt * 4 + kk) * 64 + ln) * 8] = s;
  } else if (b < 3189) {
    size_t base = ((size_t)(b - 64) * 256 + t) * 8;
    float4 v0 = *(const float4*)&x[base];
    float4 v1 = *(const float4*)&x[base + 4];
    short8 s;
    s[0] = f2bf(v0.x); s[1] = f2bf(v0.y); s[2] = f2bf(v0.z); s[3] = f2bf(v0.w);
    s[4] = f2bf(v1.x); s[5] = f2bf(v1.y); s[6] = f2bf(v1.z); s[7] = f2bf(v1.w);
    *(short8*)&y[base] = s;
  } else {
    __shared__ int lcnt[NB];
    __shared__ int loff[NB];
    __shared__ int gbase[NB];
    __shared__ int scanbuf[256];
    __shared__ int stage[4096];
    int e0 = (b - 3189) * 4096;
    for (int i = t; i < NB; i += 256) lcnt[i] = 0;
    __syncthreads();
    int d[16], s[16], r[16];
#pragma unroll
    for (int i = 0; i < 16; ++i) {
      int e = e0 + i * 256 + t;
      if (e < N_EDGES) {
        d[i] = dst[e]; s[i] = src[e];
        r[i] = atomicAdd(&lcnt[d[i] >> 8], 1);
      } else d[i] = -1;
    }
    __syncthreads();
    // exclusive scan of lcnt -> loff; reserve global ranges -> gbase
    {
      int v = (t < NB) ? lcnt[t] : 0;
      scanbuf[t] = v;
      __syncthreads();
      for (int off = 1; off < 256; off <<= 1) {
        int add = (t >= off) ? scanbuf[t - off] : 0;
        __syncthreads();
        scanbuf[t] += add;
        __syncthreads();
      }
      if (t < NB) {
        loff[t] = scanbuf[t] - v;
        gbase[t] = v ? atomicAdd(&bucket_cnt[t], v) : 0;
      }
    }
    __syncthreads();
    // scatter into LDS stage (bucket-sorted)
#pragma unroll
    for (int i = 0; i < 16; ++i) {
      if (d[i] >= 0) {
        int bb = d[i] >> 8;
        stage[loff[bb] + r[i]] = (s[i] << 8) | (d[i] & 255);
      }
    }
    __syncthreads();
    // flush contiguous runs per bucket (coalesced)
    int w = t >> 6, lane = t & 63;
    for (int bb = w; bb < NB; bb += 4) {
      int c = lcnt[bb], lo = loff[bb], gb = bb * BCAP + gbase[bb];
      for (int k = lane; k < c; k += 64) pairs[gb + k] = stage[lo + k];
    }
  }
}

// ---------------- pass2: within-bucket counting sort, 512 threads ----------------

__global__ __launch_bounds__(512) void build_pass2(const int* __restrict__ pairs,
                                                   const int* __restrict__ bucket_cnt,
                                                   int2* __restrict__ rowBE,
                                                   int* __restrict__ csr) {
  __shared__ int cnt_s[256];
  __shared__ int buf[256];
  __shared__ int ssrc[BCAP];
  int t = threadIdx.x;
  int b = blockIdx.x;
  int cnt = bucket_cnt[b];
  int gbase = b * BCAP;
  const int* pp = pairs + gbase;
  if (t < 256) cnt_s[t] = 0;
  __syncthreads();
  for (int i = t; i < cnt; i += 512) atomicAdd(&cnt_s[pp[i] & 255], 1);
  __syncthreads();
  int v = 0;
  if (t < 256) { v = cnt_s[t]; buf[t] = v; }
  __syncthreads();
  for (int off = 1; off < 256; off <<= 1) {
    int add = (t >= off && t < 256) ? buf[t - off] : 0;
    __syncthreads();
    if (t < 256) buf[t] += add;
    __syncthreads();
  }
  if (t < 256) {
    int excl = buf[t] - v;
    int node = (b << 8) + t;
    if (node < N_NODES) rowBE[node] = make_int2(gbase + excl, gbase + excl + v);
    cnt_s[t] = excl;
  }
  __syncthreads();
  for (int i = t; i < cnt; i += 512) {
    int p = pp[i];
    int pos = atomicAdd(&cnt_s[p & 255], 1);
    ssrc[pos] = p >> 8;
  }
  __syncthreads();
  for (int i = t; i < cnt; i += 512) csr[gbase + i] = ssrc[i];
}

// ---------------- gather (bf16): out = bf16(x[i] + sum_{j in N(i)} x[j]) ----------------
// register version (r7): readlane->SGPR addressing; ~3.57 TB/s = Infinity-Cache
// random-row plateau (r6-r9 depth experiments: 8->3.42, 12->3.57, LDS-DMA 32 -> 2.5)

__global__ __launch_bounds__(256, 4) void gather_bf(const unsigned short* __restrict__ x,
                                                    const int2* __restrict__ rowBE,
                                                    const int* __restrict__ csr,
                                                    unsigned short* __restrict__ out, int n) {
  int wv = __builtin_amdgcn_readfirstlane(threadIdx.x >> 6);
  int lane = threadIdx.x & 63;
  int node = blockIdx.x * 4 + wv;
  if (node >= n) return;
  int2 be = rowBE[node];
  int beg = be.x, end = be.y;
  const char* xb = (const char*)x;
  int voff = lane * 4;
  unsigned sv = *(const unsigned*)(xb + (size_t)node * 256 + voff);
  float a0 = bf_lo(sv), a1 = bf_hi(sv);
  for (int e = beg; e < end; e += 64) {
    int cnt = min(64, end - e);
    int sidx = (e + lane < end) ? csr[e + lane] : 0;
    int i = 0;
    for (; i + 32 <= cnt; i += 32) {
      unsigned v[32];
#pragma unroll
      for (int j = 0; j < 32; ++j) {
        int s = __builtin_amdgcn_readlane(sidx, i + j);   // SGPR index
        v[j] = *(const unsigned*)(xb + ((size_t)(unsigned)s << 8) + voff);
      }
#pragma unroll
      for (int j = 0; j < 32; ++j) { a0 += bf_lo(v[j]); a1 += bf_hi(v[j]); }
    }
    for (; i + 16 <= cnt; i += 16) {
      unsigned v[16];
#pragma unroll
      for (int j = 0; j < 16; ++j) {
        int s = __builtin_amdgcn_readlane(sidx, i + j);
        v[j] = *(const unsigned*)(xb + ((size_t)(unsigned)s << 8) + voff);
      }
#pragma unroll
      for (int j = 0; j < 16; ++j) { a0 += bf_lo(v[j]); a1 += bf_hi(v[j]); }
    }
    for (; i + 8 <= cnt; i += 8) {
      unsigned v[8];
#pragma unroll
      for (int j = 0; j < 8; ++j) {
        int s = __builtin_amdgcn_readlane(sidx, i + j);
        v[j] = *(const unsigned*)(xb + ((size_t)(unsigned)s << 8) + voff);
      }
#pragma unroll
      for (int j = 0; j < 8; ++j) { a0 += bf_lo(v[j]); a1 += bf_hi(v[j]); }
    }
    for (; i < cnt; ++i) {
      int s = __builtin_amdgcn_readlane(sidx, i);
      unsigned v = *(const unsigned*)(xb + ((size_t)(unsigned)s << 8) + voff);
      a0 += bf_lo(v); a1 += bf_hi(v);
    }
  }
  unsigned r = (unsigned)(unsigned short)f2bf(a0) | ((unsigned)(unsigned short)f2bf(a1) << 16);
  *(unsigned*)&out[(size_t)node * D + lane * 2] = r;
}

// ---------------- fused MLP: Out = relu(A@W1+b1)@W2 + b2 (bf16 in/out) ----------------

__global__ __launch_bounds__(256) void mlp_fused(const unsigned short* __restrict__ A,
                                                 const short* __restrict__ B1f,
                                                 const float* __restrict__ b1,
                                                 const short* __restrict__ B2f,
                                                 const float* __restrict__ b2,
                                                 unsigned short* __restrict__ Out) {
  __shared__ short hbuf[4][32 * LSTR];   // 4 waves x 8448 B
  int t = threadIdx.x;
  int w = t >> 6, lane = t & 63;
  int q = lane >> 4, m = lane & 15;
  int rowBase = blockIdx.x * 128 + w * 32;
  short* hw = hbuf[w];

  f32x4 acc[2][8] = {};
#pragma unroll
  for (int kk = 0; kk < 4; ++kk) {
    short8 a[2], b[8];
#pragma unroll
    for (int mt = 0; mt < 2; ++mt)
      a[mt] = *(const short8*)&A[(size_t)(rowBase + mt * 16 + m) * D + kk * 32 + q * 8];
#pragma unroll
    for (int nt = 0; nt < 8; ++nt)
      b[nt] = *(const short8*)&B1f[((nt * 4 + kk) * 64 + lane) * 8];
#pragma unroll
    for (int mt = 0; mt < 2; ++mt)
#pragma unroll
      for (int nt = 0; nt < 8; ++nt)
        acc[mt][nt] = __builtin_amdgcn_mfma_f32_16x16x32_bf16(a[mt], b[nt], acc[mt][nt], 0, 0, 0);
  }
  {
    float bv[8];
#pragma unroll
    for (int nt = 0; nt < 8; ++nt) bv[nt] = b1[nt * 16 + m];
#pragma unroll
    for (int mt = 0; mt < 2; ++mt)
#pragma unroll
      for (int nt = 0; nt < 8; ++nt)
#pragma unroll
        for (int r = 0; r < 4; ++r) {
          int row = mt * 16 + q * 4 + r, col = nt * 16 + m;
          hw[row * LSTR + col] = f2bf(fmaxf(acc[mt][nt][r] + bv[nt], 0.f));
        }
  }
  f32x4 acc2[2][8] = {};
#pragma unroll
  for (int kk = 0; kk < 4; ++kk) {
    short8 a[2], b[8];
#pragma unroll
    for (int mt = 0; mt < 2; ++mt)
      a[mt] = *(short8*)&hw[(mt * 16 + m) * LSTR + kk * 32 + q * 8];
#pragma unroll
    for (int nt = 0; nt < 8; ++nt)
      b[nt] = *(const short8*)&B2f[((nt * 4 + kk) * 64 + lane) * 8];
#pragma unroll
    for (int mt = 0; mt < 2; ++mt)
#pragma unroll
      for (int nt = 0; nt < 8; ++nt)
        acc2[mt][nt] = __builtin_amdgcn_mfma_f32_16x16x32_bf16(a[mt], b[nt], acc2[mt][nt], 0, 0, 0);
  }
  {
    float bv[8];
#pragma unroll
    for (int nt = 0; nt < 8; ++nt) bv[nt] = b2[nt * 16 + m];
#pragma unroll
    for (int mt = 0; mt < 2; ++mt)
#pragma unroll
      for (int nt = 0; nt < 8; ++nt)
#pragma unroll
        for (int r = 0; r < 4; ++r) {
          int row = mt * 16 + q * 4 + r, col = nt * 16 + m;
          hw[row * LSTR + col] = f2bf(acc2[mt][nt][r] + bv[nt]);
        }
  }
#pragma unroll
  for (int i = 0; i < 8; ++i) {
    int s = i * 64 + lane;
    int row = s >> 4, c8 = s & 15;
    short8 vv = *(short8*)&hw[row * LSTR + c8 * 8];
    int grow = rowBase + row;
    if (grow < N_NODES)
      *(short8*)&Out[(size_t)grow * D + c8 * 8] = vv;
  }
}

// ---------------- predictor: 256 threads, 128-cand tile, tvec computed in-block ----------------

__global__ __launch_bounds__(256, 4) void pred_kernel(const unsigned short* __restrict__ x,
                                                      const int* __restrict__ cand,
                                                      const short* __restrict__ Wf,
                                                      const int* __restrict__ ep,
                                                      const float* __restrict__ W1,
                                                      const float* __restrict__ b1,
                                                      const float* __restrict__ w2,
                                                      const float* __restrict__ b2,
                                                      float* __restrict__ out) {
  __shared__ short sS[16384];
  __shared__ short sD[16384];
  __shared__ float su[128], sv[128];
  __shared__ float partb[2][128];
  __shared__ float tvec_s[128];
  int t = threadIdx.x;
  int blockRow = blockIdx.x * 128;
  int w = t >> 6, lane = t & 63;

  // load target-edge rows (same 2 rows for all blocks -> L2 broadcast)
  if (t < 128) {
    int u = ep[0], vv = ep[1];
    su[t] = bfu(x[(size_t)u * D + t]);
    sv[t] = bfu(x[(size_t)vv * D + t]);
  }

  // stage candidate sum/absdiff fragments (random-row reads dominate this kernel)
  for (int i = 0; i < 8; ++i) {
    int idx = t + i * 256;
    int m = idx >> 4, j8 = idx & 15;
    int c = blockRow + m;
    int2 uv = ((const int2*)cand)[c];
    short8 su8 = *(const short8*)&x[(size_t)uv.x * D + j8 * 8];
    short8 sv8 = *(const short8*)&x[(size_t)uv.y * D + j8 * 8];
    short8 ss, sd;
#pragma unroll
    for (int j = 0; j < 8; ++j) {
      float uf = bfu((unsigned short)su8[j]);
      float vf = bfu((unsigned short)sv8[j]);
      ss[j] = f2bf(uf + vf);
      sd[j] = f2bf(fabsf(uf - vf));
    }
    int kk = j8 >> 2, qq = j8 & 3, mt = m >> 4, ln = (m & 15) | (qq << 4);
    int slot = ((mt * 4 + kk) * 64 + ln) * 8;
    *(short8*)&sS[slot] = ss;
    *(short8*)&sD[slot] = sd;
  }
  __syncthreads();

  // tvec[j] = b1[j] + sum_k (su+sv)_k W1[k][j] + |su-sv|_k W1[128+k][j]
  {
    int j = t & 127, seg = t >> 7;   // seg 0: sum-plane, seg 1: diff-plane
    const float* Wp = W1 + seg * 128 * D;
    float acc = 0.f;
#pragma unroll 8
    for (int k = 0; k < 128; ++k) {
      float f = seg ? fabsf(su[k] - sv[k]) : (su[k] + sv[k]);
      acc += f * Wp[k * D + j];
    }
    partb[seg][j] = acc;
  }
  __syncthreads();
  if (t < 128) tvec_s[t] = b1[t] + partb[0][t] + partb[1][t];
  __syncthreads();

  f32x4 acc[2][8] = {};
  const short* B0 = Wf + 6 * 16384;
  const short* B1 = Wf + 7 * 16384;
  for (int kk = 0; kk < 4; ++kk) {
    short8 a0[2], a1[2];
#pragma unroll
    for (int mt = 0; mt < 2; ++mt) {
      a0[mt] = *(short8*)&sS[(((w * 2 + mt) * 4 + kk) * 64 + lane) * 8];
      a1[mt] = *(short8*)&sD[(((w * 2 + mt) * 4 + kk) * 64 + lane) * 8];
    }
#pragma unroll
    for (int nt = 0; nt < 8; ++nt) {
      short8 b0 = *(const short8*)&B0[((nt * 4 + kk) * 64 + lane) * 8];
      short8 b1f = *(const short8*)&B1[((nt * 4 + kk) * 64 + lane) * 8];
#pragma unroll
      for (int mt = 0; mt < 2; ++mt) {
        acc[mt][nt] = __builtin_amdgcn_mfma_f32_16x16x32_bf16(a0[mt], b0, acc[mt][nt], 0, 0, 0);
        acc[mt][nt] = __builtin_amdgcn_mfma_f32_16x16x32_bf16(a1[mt], b1f, acc[mt][nt], 0, 0, 0);
      }
    }
  }

  int colbase = lane & 15, rq = lane >> 4;
  float tv[8], w2v[8];
#pragma unroll
  for (int nt = 0; nt < 8; ++nt) {
    tv[nt] = tvec_s[nt * 16 + colbase];
    w2v[nt] = w2[nt * 16 + colbase];
  }
  float b2v = b2[0];
#pragma unroll
  for (int mt = 0; mt < 2; ++mt) {
    float part[4] = {0.f, 0.f, 0.f, 0.f};
#pragma unroll
    for (int nt = 0; nt < 8; ++nt)
#pragma unroll
      for (int r = 0; r < 4; ++r) {
        float h = acc[mt][nt][r] + tv[nt];
        h = fmaxf(h, 0.f);
        part[r] += h * w2v[nt];
      }
#pragma unroll
    for (int r = 0; r < 4; ++r)
      for (int msk = 1; msk < 16; msk <<= 1)
        part[r] += __shfl_xor(part[r], msk, 64);
    if (colbase == 0) {
      int row0 = blockRow + (w * 2 + mt) * 16 + rq * 4;
#pragma unroll
      for (int r = 0; r < 4; ++r) out[row0 + r] = part[r] + b2v;
    }
  }
}

// ---------------- launch ----------------

extern "C" void kernel_launch(void* const* d_in, const int* in_sizes, int n_in,
                              void* d_out, int out_size, void* d_ws, size_t ws_size,
                              hipStream_t stream) {
  const float* x_in = (const float*)d_in[0];
  const int* edge_index = (const int*)d_in[1];
  const int* ep = (const int*)d_in[2];
  const int* cand = (const int*)d_in[3];
  const float* gw1 = (const float*)d_in[4];
  const float* gb1 = (const float*)d_in[5];
  const float* gw2 = (const float*)d_in[6];
  const float* gb2 = (const float*)d_in[7];
  const float* pw1 = (const float*)d_in[8];
  const float* pb1 = (const float*)d_in[9];
  const float* pw2 = (const float*)d_in[10];
  const float* pb2 = (const float*)d_in[11];
  float* out = (float*)d_out;

  char* ws = (char*)d_ws;
  size_t off = 0;
  auto alloc = [&](size_t bytes) {
    void* p = ws + off;
    off += (bytes + 255) & ~(size_t)255;
    return p;
  };
  unsigned short* xA = (unsigned short*)alloc((size_t)ROWS * D * 2);
  unsigned short* bufA = (unsigned short*)alloc((size_t)ROWS * D * 2);
  unsigned short* xB = (unsigned short*)alloc((size_t)ROWS * D * 2);
  int* pairs       = (int*)alloc((size_t)NB * BCAP * 4);
  int* csr         = (int*)alloc((size_t)NB * BCAP * 4);
  int2* rowBE      = (int2*)alloc((size_t)N_NODES * 8);
  int* bucket_cnt  = (int*)alloc((size_t)NB * 4);
  short* Wf        = (short*)alloc((size_t)8 * 16384 * 2);

  const int* src = edge_index;
  const int* dst = edge_index + N_EDGES;

  hipMemsetAsync(bucket_cnt, 0, (size_t)NB * 4, stream);
  prep_pass1<<<3580, 256, 0, stream>>>(gw1, gw2, pw1, Wf, x_in, xA, src, dst, bucket_cnt, pairs);
  build_pass2<<<NB, 512, 0, stream>>>(pairs, bucket_cnt, rowBE, csr);

  const int gemm_grid = (N_NODES + 127) / 128;
  gather_bf<<<(N_NODES + 3) / 4, 256, 0, stream>>>(xA, rowBE, csr, bufA, N_NODES);
  mlp_fused<<<gemm_grid, 256, 0, stream>>>(bufA, Wf + 0 * 16384, gb1 + 0 * D,
                                           Wf + 3 * 16384, gb2 + 0 * D, xB);
  gather_bf<<<(N_NODES + 3) / 4, 256, 0, stream>>>(xB, rowBE, csr, bufA, N_NODES);
  mlp_fused<<<gemm_grid, 256, 0, stream>>>(bufA, Wf + 1 * 16384, gb1 + 1 * D,
                                           Wf + 4 * 16384, gb2 + 1 * D, xA);
  gather_bf<<<(N_NODES + 3) / 4, 256, 0, stream>>>(xA, rowBE, csr, bufA, N_NODES);
  mlp_fused<<<gemm_grid, 256, 0, stream>>>(bufA, Wf + 2 * 16384, gb1 + 2 * D,
                                           Wf + 5 * 16384, gb2 + 2 * D, xB);

  pred_kernel<<<N_CAND / 128, 256, 0, stream>>>(xB, cand, Wf, ep, pw1, pb1, pw2, pb2, out);
}

// Round 12
// 335.857 us; speedup vs baseline: 1.1850x; 1.0407x over previous
//
#include <hip/hip_runtime.h>

#define N_NODES 50000
#define N_EDGES 1600000
#define N_CAND  131072
#define D 128
#define ROWS 50176   // padded row count
#define NB 196       // coarse buckets (dst>>8)
#define BCAP 10240   // fixed per-bucket capacity (E[cnt]=8192, sigma~90)
#define LSTR 132     // LDS row stride (bf16 elems)

typedef __attribute__((ext_vector_type(8))) short short8;
typedef __attribute__((ext_vector_type(4))) float f32x4;

__device__ inline short f2bf(float f) {
  unsigned u = __builtin_bit_cast(unsigned, f);
  u = (u + 0x7FFFu + ((u >> 16) & 1u)) >> 16;
  return (short)u;
}
__device__ inline float bf_lo(unsigned u) { return __builtin_bit_cast(float, u << 16); }
__device__ inline float bf_hi(unsigned u) { return __builtin_bit_cast(float, u & 0xFFFF0000u); }
__device__ inline float bfu(unsigned short h) { return __builtin_bit_cast(float, (unsigned)h << 16); }

// ---------------- prep + pass1 merged (r10, unchanged) ----------------

__global__ __launch_bounds__(256) void prep_pass1(const float* __restrict__ gw1,
                                                  const float* __restrict__ gw2,
                                                  const float* __restrict__ pw1,
                                                  short* __restrict__ Wf,
                                                  const float* __restrict__ x,
                                                  unsigned short* __restrict__ y,
                                                  const int* __restrict__ src,
                                                  const int* __restrict__ dst,
                                                  int* __restrict__ bucket_cnt,
                                                  int* __restrict__ pairs) {
  int b = blockIdx.x;
  int t = threadIdx.x;
  if (b < 64) {
    int tid = b * 256 + t;  // 0..16383
    int img = tid >> 11, idx = tid & 2047;
    const float* W;
    if (img < 3) W = gw1 + img * 16384;
    else if (img < 6) W = gw2 + (img - 3) * 16384;
    else W = pw1 + (256 + (img - 6) * 128) * 128;
    int n = idx & 127, k8 = idx >> 7;
    short8 s;
#pragma unroll
    for (int j = 0; j < 8; ++j) s[j] = f2bf(W[(k8 * 8 + j) * 128 + n]);
    int kk = k8 >> 2, q = k8 & 3, nt = n >> 4, ln = (n & 15) | (q << 4);
    *(short8*)&Wf[img * 16384 + ((nt * 4 + kk) * 64 + ln) * 8] = s;
  } else if (b < 3189) {
    size_t base = ((size_t)(b - 64) * 256 + t) * 8;
    float4 v0 = *(const float4*)&x[base];
    float4 v1 = *(const float4*)&x[base + 4];
    short8 s;
    s[0] = f2bf(v0.x); s[1] = f2bf(v0.y); s[2] = f2bf(v0.z); s[3] = f2bf(v0.w);
    s[4] = f2bf(v1.x); s[5] = f2bf(v1.y); s[6] = f2bf(v1.z); s[7] = f2bf(v1.w);
    *(short8*)&y[base] = s;
  } else {
    __shared__ int lcnt[NB];
    __shared__ int loff[NB];
    __shared__ int gbase[NB];
    __shared__ int scanbuf[256];
    __shared__ int stage[4096];
    int e0 = (b - 3189) * 4096;
    for (int i = t; i < NB; i += 256) lcnt[i] = 0;
    __syncthreads();
    int d[16], s[16], r[16];
#pragma unroll
    for (int i = 0; i < 16; ++i) {
      int e = e0 + i * 256 + t;
      if (e < N_EDGES) {
        d[i] = dst[e]; s[i] = src[e];
        r[i] = atomicAdd(&lcnt[d[i] >> 8], 1);
      } else d[i] = -1;
    }
    __syncthreads();
    {
      int v = (t < NB) ? lcnt[t] : 0;
      scanbuf[t] = v;
      __syncthreads();
      for (int off = 1; off < 256; off <<= 1) {
        int add = (t >= off) ? scanbuf[t - off] : 0;
        __syncthreads();
        scanbuf[t] += add;
        __syncthreads();
      }
      if (t < NB) {
        loff[t] = scanbuf[t] - v;
        gbase[t] = v ? atomicAdd(&bucket_cnt[t], v) : 0;
      }
    }
    __syncthreads();
#pragma unroll
    for (int i = 0; i < 16; ++i) {
      if (d[i] >= 0) {
        int bb = d[i] >> 8;
        stage[loff[bb] + r[i]] = (s[i] << 8) | (d[i] & 255);
      }
    }
    __syncthreads();
    int w = t >> 6, lane = t & 63;
    for (int bb = w; bb < NB; bb += 4) {
      int c = lcnt[bb], lo = loff[bb], gb = bb * BCAP + gbase[bb];
      for (int k = lane; k < c; k += 64) pairs[gb + k] = stage[lo + k];
    }
  }
}

// ---------------- pass2: within-bucket counting sort (r10, unchanged) ----------------

__global__ __launch_bounds__(512) void build_pass2(const int* __restrict__ pairs,
                                                   const int* __restrict__ bucket_cnt,
                                                   int2* __restrict__ rowBE,
                                                   int* __restrict__ csr) {
  __shared__ int cnt_s[256];
  __shared__ int buf[256];
  __shared__ int ssrc[BCAP];
  int t = threadIdx.x;
  int b = blockIdx.x;
  int cnt = bucket_cnt[b];
  int gbase = b * BCAP;
  const int* pp = pairs + gbase;
  if (t < 256) cnt_s[t] = 0;
  __syncthreads();
  for (int i = t; i < cnt; i += 512) atomicAdd(&cnt_s[pp[i] & 255], 1);
  __syncthreads();
  int v = 0;
  if (t < 256) { v = cnt_s[t]; buf[t] = v; }
  __syncthreads();
  for (int off = 1; off < 256; off <<= 1) {
    int add = (t >= off && t < 256) ? buf[t - off] : 0;
    __syncthreads();
    if (t < 256) buf[t] += add;
    __syncthreads();
  }
  if (t < 256) {
    int excl = buf[t] - v;
    int node = (b << 8) + t;
    if (node < N_NODES) rowBE[node] = make_int2(gbase + excl, gbase + excl + v);
    cnt_s[t] = excl;
  }
  __syncthreads();
  for (int i = t; i < cnt; i += 512) {
    int p = pp[i];
    int pos = atomicAdd(&cnt_s[p & 255], 1);
    ssrc[pos] = p >> 8;
  }
  __syncthreads();
  for (int i = t; i < cnt; i += 512) csr[gbase + i] = ssrc[i];
}

// ---------------- fused GIN layer: block-local gather(16 nodes) + 16-row MLP ----------------
// Wave w gathers 4 nodes (same 12500-wave parallelism/batching as the proven 46.6us
// standalone gather) into a 4.2KB shared tile; then all 4 waves cooperatively run the
// 16-row MLP (2 nt-frags/wave). No grid-wide sync, no bufA round-trip.

__global__ __launch_bounds__(256) void gin_layer(const unsigned short* __restrict__ xin,
                                                 const int2* __restrict__ rowBE,
                                                 const int* __restrict__ csr,
                                                 const short* __restrict__ B1f,
                                                 const float* __restrict__ b1,
                                                 const short* __restrict__ B2f,
                                                 const float* __restrict__ b2,
                                                 unsigned short* __restrict__ xout) {
  __shared__ short hbuf[16 * LSTR];   // 4224 B
  int t = threadIdx.x;
  int w = t >> 6, lane = t & 63;
  int node0 = blockIdx.x * 16;        // grid 3125: exact cover of 50000
  const char* xb = (const char*)xin;
  int voff = lane * 4;

  // ---- gather: 4 sequential nodes per wave ----
  for (int i = 0; i < 4; ++i) {
    int node = node0 + w * 4 + i;
    int2 be = rowBE[node];
    int beg = be.x, end = be.y;
    unsigned sv = *(const unsigned*)(xb + (size_t)node * 256 + voff);
    float a0 = bf_lo(sv), a1 = bf_hi(sv);
    for (int e = beg; e < end; e += 64) {
      int cnt = min(64, end - e);
      int sidx = (e + lane < end) ? csr[e + lane] : 0;
      int ii = 0;
      for (; ii + 32 <= cnt; ii += 32) {
        unsigned v[32];
#pragma unroll
        for (int j = 0; j < 32; ++j) {
          int s = __builtin_amdgcn_readlane(sidx, ii + j);   // SGPR index
          v[j] = *(const unsigned*)(xb + ((size_t)(unsigned)s << 8) + voff);
        }
#pragma unroll
        for (int j = 0; j < 32; ++j) { a0 += bf_lo(v[j]); a1 += bf_hi(v[j]); }
      }
      for (; ii + 16 <= cnt; ii += 16) {
        unsigned v[16];
#pragma unroll
        for (int j = 0; j < 16; ++j) {
          int s = __builtin_amdgcn_readlane(sidx, ii + j);
          v[j] = *(const unsigned*)(xb + ((size_t)(unsigned)s << 8) + voff);
        }
#pragma unroll
        for (int j = 0; j < 16; ++j) { a0 += bf_lo(v[j]); a1 += bf_hi(v[j]); }
      }
      for (; ii + 8 <= cnt; ii += 8) {
        unsigned v[8];
#pragma unroll
        for (int j = 0; j < 8; ++j) {
          int s = __builtin_amdgcn_readlane(sidx, ii + j);
          v[j] = *(const unsigned*)(xb + ((size_t)(unsigned)s << 8) + voff);
        }
#pragma unroll
        for (int j = 0; j < 8; ++j) { a0 += bf_lo(v[j]); a1 += bf_hi(v[j]); }
      }
      for (; ii < cnt; ++ii) {
        int s = __builtin_amdgcn_readlane(sidx, ii);
        unsigned v = *(const unsigned*)(xb + ((size_t)(unsigned)s << 8) + voff);
        a0 += bf_lo(v); a1 += bf_hi(v);
      }
    }
    unsigned r = (unsigned)(unsigned short)f2bf(a0) | ((unsigned)(unsigned short)f2bf(a1) << 16);
    *(unsigned*)&hbuf[(w * 4 + i) * LSTR + lane * 2] = r;
  }
  __syncthreads();

  // ---- MLP on the 16-row tile; wave w owns nt = {2w, 2w+1} ----
  int q = lane >> 4, m = lane & 15;
  short8 a0f[4];
#pragma unroll
  for (int kk = 0; kk < 4; ++kk)
    a0f[kk] = *(short8*)&hbuf[m * LSTR + kk * 32 + q * 8];
  __syncthreads();   // all a-frags in regs before h1 overwrites hbuf

  f32x4 acc[2] = {};
#pragma unroll
  for (int kk = 0; kk < 4; ++kk)
#pragma unroll
    for (int j = 0; j < 2; ++j) {
      int nt = w * 2 + j;
      short8 bf = *(const short8*)&B1f[((nt * 4 + kk) * 64 + lane) * 8];
      acc[j] = __builtin_amdgcn_mfma_f32_16x16x32_bf16(a0f[kk], bf, acc[j], 0, 0, 0);
    }
#pragma unroll
  for (int j = 0; j < 2; ++j) {
    int nt = w * 2 + j;
    float bv = b1[nt * 16 + m];
#pragma unroll
    for (int r = 0; r < 4; ++r)
      hbuf[(q * 4 + r) * LSTR + nt * 16 + m] = f2bf(fmaxf(acc[j][r] + bv, 0.f));
  }
  __syncthreads();

  short8 a1f[4];
#pragma unroll
  for (int kk = 0; kk < 4; ++kk)
    a1f[kk] = *(short8*)&hbuf[m * LSTR + kk * 32 + q * 8];
  __syncthreads();   // all h1-frags in regs before C overwrites hbuf

  f32x4 acc2[2] = {};
#pragma unroll
  for (int kk = 0; kk < 4; ++kk)
#pragma unroll
    for (int j = 0; j < 2; ++j) {
      int nt = w * 2 + j;
      short8 bf = *(const short8*)&B2f[((nt * 4 + kk) * 64 + lane) * 8];
      acc2[j] = __builtin_amdgcn_mfma_f32_16x16x32_bf16(a1f[kk], bf, acc2[j], 0, 0, 0);
    }
#pragma unroll
  for (int j = 0; j < 2; ++j) {
    int nt = w * 2 + j;
    float bv = b2[nt * 16 + m];
#pragma unroll
    for (int r = 0; r < 4; ++r)
      hbuf[(q * 4 + r) * LSTR + nt * 16 + m] = f2bf(acc2[j][r] + bv);
  }
  __syncthreads();

  // coalesced flush: 16 rows x 128 cols, one short8 per thread
  {
    int row = t >> 4, c8 = t & 15;
    short8 vv = *(short8*)&hbuf[row * LSTR + c8 * 8];
    *(short8*)&xout[(size_t)(node0 + row) * D + c8 * 8] = vv;
  }
}

// ---------------- predictor (r10 + staging unroll) ----------------

__global__ __launch_bounds__(256, 4) void pred_kernel(const unsigned short* __restrict__ x,
                                                      const int* __restrict__ cand,
                                                      const short* __restrict__ Wf,
                                                      const int* __restrict__ ep,
                                                      const float* __restrict__ W1,
                                                      const float* __restrict__ b1,
                                                      const float* __restrict__ w2,
                                                      const float* __restrict__ b2,
                                                      float* __restrict__ out) {
  __shared__ short sS[16384];
  __shared__ short sD[16384];
  __shared__ float su[128], sv[128];
  __shared__ float partb[2][128];
  __shared__ float tvec_s[128];
  int t = threadIdx.x;
  int blockRow = blockIdx.x * 128;
  int w = t >> 6, lane = t & 63;

  if (t < 128) {
    int u = ep[0], vv = ep[1];
    su[t] = bfu(x[(size_t)u * D + t]);
    sv[t] = bfu(x[(size_t)vv * D + t]);
  }

#pragma unroll 2
  for (int i = 0; i < 8; ++i) {
    int idx = t + i * 256;
    int m = idx >> 4, j8 = idx & 15;
    int c = blockRow + m;
    int2 uv = ((const int2*)cand)[c];
    short8 su8 = *(const short8*)&x[(size_t)uv.x * D + j8 * 8];
    short8 sv8 = *(const short8*)&x[(size_t)uv.y * D + j8 * 8];
    short8 ss, sd;
#pragma unroll
    for (int j = 0; j < 8; ++j) {
      float uf = bfu((unsigned short)su8[j]);
      float vf = bfu((unsigned short)sv8[j]);
      ss[j] = f2bf(uf + vf);
      sd[j] = f2bf(fabsf(uf - vf));
    }
    int kk = j8 >> 2, qq = j8 & 3, mt = m >> 4, ln = (m & 15) | (qq << 4);
    int slot = ((mt * 4 + kk) * 64 + ln) * 8;
    *(short8*)&sS[slot] = ss;
    *(short8*)&sD[slot] = sd;
  }
  __syncthreads();

  {
    int j = t & 127, seg = t >> 7;
    const float* Wp = W1 + seg * 128 * D;
    float acc = 0.f;
#pragma unroll 8
    for (int k = 0; k < 128; ++k) {
      float f = seg ? fabsf(su[k] - sv[k]) : (su[k] + sv[k]);
      acc += f * Wp[k * D + j];
    }
    partb[seg][j] = acc;
  }
  __syncthreads();
  if (t < 128) tvec_s[t] = b1[t] + partb[0][t] + partb[1][t];
  __syncthreads();

  f32x4 acc[2][8] = {};
  const short* B0 = Wf + 6 * 16384;
  const short* B1 = Wf + 7 * 16384;
  for (int kk = 0; kk < 4; ++kk) {
    short8 a0[2], a1[2];
#pragma unroll
    for (int mt = 0; mt < 2; ++mt) {
      a0[mt] = *(short8*)&sS[(((w * 2 + mt) * 4 + kk) * 64 + lane) * 8];
      a1[mt] = *(short8*)&sD[(((w * 2 + mt) * 4 + kk) * 64 + lane) * 8];
    }
#pragma unroll
    for (int nt = 0; nt < 8; ++nt) {
      short8 b0 = *(const short8*)&B0[((nt * 4 + kk) * 64 + lane) * 8];
      short8 b1f = *(const short8*)&B1[((nt * 4 + kk) * 64 + lane) * 8];
#pragma unroll
      for (int mt = 0; mt < 2; ++mt) {
        acc[mt][nt] = __builtin_amdgcn_mfma_f32_16x16x32_bf16(a0[mt], b0, acc[mt][nt], 0, 0, 0);
        acc[mt][nt] = __builtin_amdgcn_mfma_f32_16x16x32_bf16(a1[mt], b1f, acc[mt][nt], 0, 0, 0);
      }
    }
  }

  int colbase = lane & 15, rq = lane >> 4;
  float tv[8], w2v[8];
#pragma unroll
  for (int nt = 0; nt < 8; ++nt) {
    tv[nt] = tvec_s[nt * 16 + colbase];
    w2v[nt] = w2[nt * 16 + colbase];
  }
  float b2v = b2[0];
#pragma unroll
  for (int mt = 0; mt < 2; ++mt) {
    float part[4] = {0.f, 0.f, 0.f, 0.f};
#pragma unroll
    for (int nt = 0; nt < 8; ++nt)
#pragma unroll
      for (int r = 0; r < 4; ++r) {
        float h = acc[mt][nt][r] + tv[nt];
        h = fmaxf(h, 0.f);
        part[r] += h * w2v[nt];
      }
#pragma unroll
    for (int r = 0; r < 4; ++r)
      for (int msk = 1; msk < 16; msk <<= 1)
        part[r] += __shfl_xor(part[r], msk, 64);
    if (colbase == 0) {
      int row0 = blockRow + (w * 2 + mt) * 16 + rq * 4;
#pragma unroll
      for (int r = 0; r < 4; ++r) out[row0 + r] = part[r] + b2v;
    }
  }
}

// ---------------- launch ----------------

extern "C" void kernel_launch(void* const* d_in, const int* in_sizes, int n_in,
                              void* d_out, int out_size, void* d_ws, size_t ws_size,
                              hipStream_t stream) {
  const float* x_in = (const float*)d_in[0];
  const int* edge_index = (const int*)d_in[1];
  const int* ep = (const int*)d_in[2];
  const int* cand = (const int*)d_in[3];
  const float* gw1 = (const float*)d_in[4];
  const float* gb1 = (const float*)d_in[5];
  const float* gw2 = (const float*)d_in[6];
  const float* gb2 = (const float*)d_in[7];
  const float* pw1 = (const float*)d_in[8];
  const float* pb1 = (const float*)d_in[9];
  const float* pw2 = (const float*)d_in[10];
  const float* pb2 = (const float*)d_in[11];
  float* out = (float*)d_out;

  char* ws = (char*)d_ws;
  size_t off = 0;
  auto alloc = [&](size_t bytes) {
    void* p = ws + off;
    off += (bytes + 255) & ~(size_t)255;
    return p;
  };
  unsigned short* xA = (unsigned short*)alloc((size_t)ROWS * D * 2);
  unsigned short* xB = (unsigned short*)alloc((size_t)ROWS * D * 2);
  int* pairs       = (int*)alloc((size_t)NB * BCAP * 4);
  int* csr         = (int*)alloc((size_t)NB * BCAP * 4);
  int2* rowBE      = (int2*)alloc((size_t)N_NODES * 8);
  int* bucket_cnt  = (int*)alloc((size_t)NB * 4);
  short* Wf        = (short*)alloc((size_t)8 * 16384 * 2);

  const int* src = edge_index;
  const int* dst = edge_index + N_EDGES;

  hipMemsetAsync(bucket_cnt, 0, (size_t)NB * 4, stream);
  prep_pass1<<<3580, 256, 0, stream>>>(gw1, gw2, pw1, Wf, x_in, xA, src, dst, bucket_cnt, pairs);
  build_pass2<<<NB, 512, 0, stream>>>(pairs, bucket_cnt, rowBE, csr);

  const int gin_grid = N_NODES / 16;  // 3125
  gin_layer<<<gin_grid, 256, 0, stream>>>(xA, rowBE, csr, Wf + 0 * 16384, gb1 + 0 * D,
                                          Wf + 3 * 16384, gb2 + 0 * D, xB);
  gin_layer<<<gin_grid, 256, 0, stream>>>(xB, rowBE, csr, Wf + 1 * 16384, gb1 + 1 * D,
                                          Wf + 4 * 16384, gb2 + 1 * D, xA);
  gin_layer<<<gin_grid, 256, 0, stream>>>(xA, rowBE, csr, Wf + 2 * 16384, gb1 + 2 * D,
                                          Wf + 5 * 16384, gb2 + 2 * D, xB);

  pred_kernel<<<N_CAND / 128, 256, 0, stream>>>(xB, cand, Wf, ep, pw1, pb1, pw2, pb2, out);
}

// Round 13
// 333.943 us; speedup vs baseline: 1.1917x; 1.0057x over previous
//
#include <hip/hip_runtime.h>

#define N_NODES 50000
#define N_EDGES 1600000
#define N_CAND  131072
#define D 128
#define ROWS 50176   // padded row count
#define NB 196       // coarse buckets (dst>>8)
#define BCAP 10240   // fixed per-bucket capacity (E[cnt]=8192, sigma~90)
#define LSTR 132     // LDS row stride (bf16 elems)

typedef __attribute__((ext_vector_type(8))) short short8;
typedef __attribute__((ext_vector_type(4))) float f32x4;

__device__ inline short f2bf(float f) {
  unsigned u = __builtin_bit_cast(unsigned, f);
  u = (u + 0x7FFFu + ((u >> 16) & 1u)) >> 16;
  return (short)u;
}
__device__ inline float bf_lo(unsigned u) { return __builtin_bit_cast(float, u << 16); }
__device__ inline float bf_hi(unsigned u) { return __builtin_bit_cast(float, u & 0xFFFF0000u); }
__device__ inline float bfu(unsigned short h) { return __builtin_bit_cast(float, (unsigned)h << 16); }

// ---------------- prep + pass1 merged (r10, unchanged) ----------------

__global__ __launch_bounds__(256) void prep_pass1(const float* __restrict__ gw1,
                                                  const float* __restrict__ gw2,
                                                  const float* __restrict__ pw1,
                                                  short* __restrict__ Wf,
                                                  const float* __restrict__ x,
                                                  unsigned short* __restrict__ y,
                                                  const int* __restrict__ src,
                                                  const int* __restrict__ dst,
                                                  int* __restrict__ bucket_cnt,
                                                  int* __restrict__ pairs) {
  int b = blockIdx.x;
  int t = threadIdx.x;
  if (b < 64) {
    int tid = b * 256 + t;  // 0..16383
    int img = tid >> 11, idx = tid & 2047;
    const float* W;
    if (img < 3) W = gw1 + img * 16384;
    else if (img < 6) W = gw2 + (img - 3) * 16384;
    else W = pw1 + (256 + (img - 6) * 128) * 128;
    int n = idx & 127, k8 = idx >> 7;
    short8 s;
#pragma unroll
    for (int j = 0; j < 8; ++j) s[j] = f2bf(W[(k8 * 8 + j) * 128 + n]);
    int kk = k8 >> 2, q = k8 & 3, nt = n >> 4, ln = (n & 15) | (q << 4);
    *(short8*)&Wf[img * 16384 + ((nt * 4 + kk) * 64 + ln) * 8] = s;
  } else if (b < 3189) {
    size_t base = ((size_t)(b - 64) * 256 + t) * 8;
    float4 v0 = *(const float4*)&x[base];
    float4 v1 = *(const float4*)&x[base + 4];
    short8 s;
    s[0] = f2bf(v0.x); s[1] = f2bf(v0.y); s[2] = f2bf(v0.z); s[3] = f2bf(v0.w);
    s[4] = f2bf(v1.x); s[5] = f2bf(v1.y); s[6] = f2bf(v1.z); s[7] = f2bf(v1.w);
    *(short8*)&y[base] = s;
  } else {
    __shared__ int lcnt[NB];
    __shared__ int loff[NB];
    __shared__ int gbase[NB];
    __shared__ int scanbuf[256];
    __shared__ int stage[4096];
    int e0 = (b - 3189) * 4096;
    for (int i = t; i < NB; i += 256) lcnt[i] = 0;
    __syncthreads();
    int d[16], s[16], r[16];
#pragma unroll
    for (int i = 0; i < 16; ++i) {
      int e = e0 + i * 256 + t;
      if (e < N_EDGES) {
        d[i] = dst[e]; s[i] = src[e];
        r[i] = atomicAdd(&lcnt[d[i] >> 8], 1);
      } else d[i] = -1;
    }
    __syncthreads();
    {
      int v = (t < NB) ? lcnt[t] : 0;
      scanbuf[t] = v;
      __syncthreads();
      for (int off = 1; off < 256; off <<= 1) {
        int add = (t >= off) ? scanbuf[t - off] : 0;
        __syncthreads();
        scanbuf[t] += add;
        __syncthreads();
      }
      if (t < NB) {
        loff[t] = scanbuf[t] - v;
        gbase[t] = v ? atomicAdd(&bucket_cnt[t], v) : 0;
      }
    }
    __syncthreads();
#pragma unroll
    for (int i = 0; i < 16; ++i) {
      if (d[i] >= 0) {
        int bb = d[i] >> 8;
        stage[loff[bb] + r[i]] = (s[i] << 8) | (d[i] & 255);
      }
    }
    __syncthreads();
    int w = t >> 6, lane = t & 63;
    for (int bb = w; bb < NB; bb += 4) {
      int c = lcnt[bb], lo = loff[bb], gb = bb * BCAP + gbase[bb];
      for (int k = lane; k < c; k += 64) pairs[gb + k] = stage[lo + k];
    }
  }
}

// ---------------- pass2: within-bucket counting sort (r10, unchanged) ----------------

__global__ __launch_bounds__(512) void build_pass2(const int* __restrict__ pairs,
                                                   const int* __restrict__ bucket_cnt,
                                                   int2* __restrict__ rowBE,
                                                   int* __restrict__ csr) {
  __shared__ int cnt_s[256];
  __shared__ int buf[256];
  __shared__ int ssrc[BCAP];
  int t = threadIdx.x;
  int b = blockIdx.x;
  int cnt = bucket_cnt[b];
  int gbase = b * BCAP;
  const int* pp = pairs + gbase;
  if (t < 256) cnt_s[t] = 0;
  __syncthreads();
  for (int i = t; i < cnt; i += 512) atomicAdd(&cnt_s[pp[i] & 255], 1);
  __syncthreads();
  int v = 0;
  if (t < 256) { v = cnt_s[t]; buf[t] = v; }
  __syncthreads();
  for (int off = 1; off < 256; off <<= 1) {
    int add = (t >= off && t < 256) ? buf[t - off] : 0;
    __syncthreads();
    if (t < 256) buf[t] += add;
    __syncthreads();
  }
  if (t < 256) {
    int excl = buf[t] - v;
    int node = (b << 8) + t;
    if (node < N_NODES) rowBE[node] = make_int2(gbase + excl, gbase + excl + v);
    cnt_s[t] = excl;
  }
  __syncthreads();
  for (int i = t; i < cnt; i += 512) {
    int p = pp[i];
    int pos = atomicAdd(&cnt_s[p & 255], 1);
    ssrc[pos] = p >> 8;
  }
  __syncthreads();
  for (int i = t; i < cnt; i += 512) csr[gbase + i] = ssrc[i];
}

// ---------------- fused GIN layer (r12, unchanged): block-local gather + 16-row MLP ----------------

__global__ __launch_bounds__(256) void gin_layer(const unsigned short* __restrict__ xin,
                                                 const int2* __restrict__ rowBE,
                                                 const int* __restrict__ csr,
                                                 const short* __restrict__ B1f,
                                                 const float* __restrict__ b1,
                                                 const short* __restrict__ B2f,
                                                 const float* __restrict__ b2,
                                                 unsigned short* __restrict__ xout) {
  __shared__ short hbuf[16 * LSTR];   // 4224 B
  int t = threadIdx.x;
  int w = t >> 6, lane = t & 63;
  int node0 = blockIdx.x * 16;        // grid 3125: exact cover of 50000
  const char* xb = (const char*)xin;
  int voff = lane * 4;

  for (int i = 0; i < 4; ++i) {
    int node = node0 + w * 4 + i;
    int2 be = rowBE[node];
    int beg = be.x, end = be.y;
    unsigned sv = *(const unsigned*)(xb + (size_t)node * 256 + voff);
    float a0 = bf_lo(sv), a1 = bf_hi(sv);
    for (int e = beg; e < end; e += 64) {
      int cnt = min(64, end - e);
      int sidx = (e + lane < end) ? csr[e + lane] : 0;
      int ii = 0;
      for (; ii + 32 <= cnt; ii += 32) {
        unsigned v[32];
#pragma unroll
        for (int j = 0; j < 32; ++j) {
          int s = __builtin_amdgcn_readlane(sidx, ii + j);   // SGPR index
          v[j] = *(const unsigned*)(xb + ((size_t)(unsigned)s << 8) + voff);
        }
#pragma unroll
        for (int j = 0; j < 32; ++j) { a0 += bf_lo(v[j]); a1 += bf_hi(v[j]); }
      }
      for (; ii + 16 <= cnt; ii += 16) {
        unsigned v[16];
#pragma unroll
        for (int j = 0; j < 16; ++j) {
          int s = __builtin_amdgcn_readlane(sidx, ii + j);
          v[j] = *(const unsigned*)(xb + ((size_t)(unsigned)s << 8) + voff);
        }
#pragma unroll
        for (int j = 0; j < 16; ++j) { a0 += bf_lo(v[j]); a1 += bf_hi(v[j]); }
      }
      for (; ii + 8 <= cnt; ii += 8) {
        unsigned v[8];
#pragma unroll
        for (int j = 0; j < 8; ++j) {
          int s = __builtin_amdgcn_readlane(sidx, ii + j);
          v[j] = *(const unsigned*)(xb + ((size_t)(unsigned)s << 8) + voff);
        }
#pragma unroll
        for (int j = 0; j < 8; ++j) { a0 += bf_lo(v[j]); a1 += bf_hi(v[j]); }
      }
      for (; ii < cnt; ++ii) {
        int s = __builtin_amdgcn_readlane(sidx, ii);
        unsigned v = *(const unsigned*)(xb + ((size_t)(unsigned)s << 8) + voff);
        a0 += bf_lo(v); a1 += bf_hi(v);
      }
    }
    unsigned r = (unsigned)(unsigned short)f2bf(a0) | ((unsigned)(unsigned short)f2bf(a1) << 16);
    *(unsigned*)&hbuf[(w * 4 + i) * LSTR + lane * 2] = r;
  }
  __syncthreads();

  int q = lane >> 4, m = lane & 15;
  short8 a0f[4];
#pragma unroll
  for (int kk = 0; kk < 4; ++kk)
    a0f[kk] = *(short8*)&hbuf[m * LSTR + kk * 32 + q * 8];
  __syncthreads();

  f32x4 acc[2] = {};
#pragma unroll
  for (int kk = 0; kk < 4; ++kk)
#pragma unroll
    for (int j = 0; j < 2; ++j) {
      int nt = w * 2 + j;
      short8 bf = *(const short8*)&B1f[((nt * 4 + kk) * 64 + lane) * 8];
      acc[j] = __builtin_amdgcn_mfma_f32_16x16x32_bf16(a0f[kk], bf, acc[j], 0, 0, 0);
    }
#pragma unroll
  for (int j = 0; j < 2; ++j) {
    int nt = w * 2 + j;
    float bv = b1[nt * 16 + m];
#pragma unroll
    for (int r = 0; r < 4; ++r)
      hbuf[(q * 4 + r) * LSTR + nt * 16 + m] = f2bf(fmaxf(acc[j][r] + bv, 0.f));
  }
  __syncthreads();

  short8 a1f[4];
#pragma unroll
  for (int kk = 0; kk < 4; ++kk)
    a1f[kk] = *(short8*)&hbuf[m * LSTR + kk * 32 + q * 8];
  __syncthreads();

  f32x4 acc2[2] = {};
#pragma unroll
  for (int kk = 0; kk < 4; ++kk)
#pragma unroll
    for (int j = 0; j < 2; ++j) {
      int nt = w * 2 + j;
      short8 bf = *(const short8*)&B2f[((nt * 4 + kk) * 64 + lane) * 8];
      acc2[j] = __builtin_amdgcn_mfma_f32_16x16x32_bf16(a1f[kk], bf, acc2[j], 0, 0, 0);
    }
#pragma unroll
  for (int j = 0; j < 2; ++j) {
    int nt = w * 2 + j;
    float bv = b2[nt * 16 + m];
#pragma unroll
    for (int r = 0; r < 4; ++r)
      hbuf[(q * 4 + r) * LSTR + nt * 16 + m] = f2bf(acc2[j][r] + bv);
  }
  __syncthreads();

  {
    int row = t >> 4, c8 = t & 15;
    short8 vv = *(short8*)&hbuf[row * LSTR + c8 * 8];
    *(short8*)&xout[(size_t)(node0 + row) * D + c8 * 8] = vv;
  }
}

// ---------------- predictor: explicit 16-deep prefetch staging ----------------

__global__ __launch_bounds__(256, 4) void pred_kernel(const unsigned short* __restrict__ x,
                                                      const int* __restrict__ cand,
                                                      const short* __restrict__ Wf,
                                                      const int* __restrict__ ep,
                                                      const float* __restrict__ W1,
                                                      const float* __restrict__ b1,
                                                      const float* __restrict__ w2,
                                                      const float* __restrict__ b2,
                                                      float* __restrict__ out) {
  __shared__ short sS[16384];
  __shared__ short sD[16384];
  __shared__ float su[128], sv[128];
  __shared__ float partb[2][128];
  __shared__ float tvec_s[128];
  int t = threadIdx.x;
  int blockRow = blockIdx.x * 128;
  int w = t >> 6, lane = t & 63;

  if (t < 128) {
    int u = ep[0], vv = ep[1];
    su[t] = bfu(x[(size_t)u * D + t]);
    sv[t] = bfu(x[(size_t)vv * D + t]);
  }

  // prefetch burst: 16 independent 16B loads per thread (128 lines in flight per wave)
  short8 U[8], V[8];
#pragma unroll
  for (int i = 0; i < 8; ++i) {
    int idx = t + i * 256;
    int c = blockRow + (idx >> 4);
    int2 uv = ((const int2*)cand)[c];
    int j8 = idx & 15;
    U[i] = *(const short8*)&x[(size_t)uv.x * D + j8 * 8];
    V[i] = *(const short8*)&x[(size_t)uv.y * D + j8 * 8];
  }
#pragma unroll
  for (int i = 0; i < 8; ++i) {
    int idx = t + i * 256;
    int m = idx >> 4, j8 = idx & 15;
    short8 ss, sd;
#pragma unroll
    for (int j = 0; j < 8; ++j) {
      float uf = bfu((unsigned short)U[i][j]);
      float vf = bfu((unsigned short)V[i][j]);
      ss[j] = f2bf(uf + vf);
      sd[j] = f2bf(fabsf(uf - vf));
    }
    int kk = j8 >> 2, qq = j8 & 3, mt = m >> 4, ln = (m & 15) | (qq << 4);
    int slot = ((mt * 4 + kk) * 64 + ln) * 8;
    *(short8*)&sS[slot] = ss;
    *(short8*)&sD[slot] = sd;
  }
  __syncthreads();

  {
    int j = t & 127, seg = t >> 7;
    const float* Wp = W1 + seg * 128 * D;
    float acc = 0.f;
#pragma unroll 8
    for (int k = 0; k < 128; ++k) {
      float f = seg ? fabsf(su[k] - sv[k]) : (su[k] + sv[k]);
      acc += f * Wp[k * D + j];
    }
    partb[seg][j] = acc;
  }
  __syncthreads();
  if (t < 128) tvec_s[t] = b1[t] + partb[0][t] + partb[1][t];
  __syncthreads();

  f32x4 acc[2][8] = {};
  const short* B0 = Wf + 6 * 16384;
  const short* B1 = Wf + 7 * 16384;
  for (int kk = 0; kk < 4; ++kk) {
    short8 a0[2], a1[2];
#pragma unroll
    for (int mt = 0; mt < 2; ++mt) {
      a0[mt] = *(short8*)&sS[(((w * 2 + mt) * 4 + kk) * 64 + lane) * 8];
      a1[mt] = *(short8*)&sD[(((w * 2 + mt) * 4 + kk) * 64 + lane) * 8];
    }
#pragma unroll
    for (int nt = 0; nt < 8; ++nt) {
      short8 b0 = *(const short8*)&B0[((nt * 4 + kk) * 64 + lane) * 8];
      short8 b1f = *(const short8*)&B1[((nt * 4 + kk) * 64 + lane) * 8];
#pragma unroll
      for (int mt = 0; mt < 2; ++mt) {
        acc[mt][nt] = __builtin_amdgcn_mfma_f32_16x16x32_bf16(a0[mt], b0, acc[mt][nt], 0, 0, 0);
        acc[mt][nt] = __builtin_amdgcn_mfma_f32_16x16x32_bf16(a1[mt], b1f, acc[mt][nt], 0, 0, 0);
      }
    }
  }

  int colbase = lane & 15, rq = lane >> 4;
  float tv[8], w2v[8];
#pragma unroll
  for (int nt = 0; nt < 8; ++nt) {
    tv[nt] = tvec_s[nt * 16 + colbase];
    w2v[nt] = w2[nt * 16 + colbase];
  }
  float b2v = b2[0];
#pragma unroll
  for (int mt = 0; mt < 2; ++mt) {
    float part[4] = {0.f, 0.f, 0.f, 0.f};
#pragma unroll
    for (int nt = 0; nt < 8; ++nt)
#pragma unroll
      for (int r = 0; r < 4; ++r) {
        float h = acc[mt][nt][r] + tv[nt];
        h = fmaxf(h, 0.f);
        part[r] += h * w2v[nt];
      }
#pragma unroll
    for (int r = 0; r < 4; ++r)
      for (int msk = 1; msk < 16; msk <<= 1)
        part[r] += __shfl_xor(part[r], msk, 64);
    if (colbase == 0) {
      int row0 = blockRow + (w * 2 + mt) * 16 + rq * 4;
#pragma unroll
      for (int r = 0; r < 4; ++r) out[row0 + r] = part[r] + b2v;
    }
  }
}

// ---------------- launch ----------------

extern "C" void kernel_launch(void* const* d_in, const int* in_sizes, int n_in,
                              void* d_out, int out_size, void* d_ws, size_t ws_size,
                              hipStream_t stream) {
  const float* x_in = (const float*)d_in[0];
  const int* edge_index = (const int*)d_in[1];
  const int* ep = (const int*)d_in[2];
  const int* cand = (const int*)d_in[3];
  const float* gw1 = (const float*)d_in[4];
  const float* gb1 = (const float*)d_in[5];
  const float* gw2 = (const float*)d_in[6];
  const float* gb2 = (const float*)d_in[7];
  const float* pw1 = (const float*)d_in[8];
  const float* pb1 = (const float*)d_in[9];
  const float* pw2 = (const float*)d_in[10];
  const float* pb2 = (const float*)d_in[11];
  float* out = (float*)d_out;

  char* ws = (char*)d_ws;
  size_t off = 0;
  auto alloc = [&](size_t bytes) {
    void* p = ws + off;
    off += (bytes + 255) & ~(size_t)255;
    return p;
  };
  unsigned short* xA = (unsigned short*)alloc((size_t)ROWS * D * 2);
  unsigned short* xB = (unsigned short*)alloc((size_t)ROWS * D * 2);
  int* pairs       = (int*)alloc((size_t)NB * BCAP * 4);
  int* csr         = (int*)alloc((size_t)NB * BCAP * 4);
  int2* rowBE      = (int2*)alloc((size_t)N_NODES * 8);
  int* bucket_cnt  = (int*)alloc((size_t)NB * 4);
  short* Wf        = (short*)alloc((size_t)8 * 16384 * 2);

  const int* src = edge_index;
  const int* dst = edge_index + N_EDGES;

  hipMemsetAsync(bucket_cnt, 0, (size_t)NB * 4, stream);
  prep_pass1<<<3580, 256, 0, stream>>>(gw1, gw2, pw1, Wf, x_in, xA, src, dst, bucket_cnt, pairs);
  build_pass2<<<NB, 512, 0, stream>>>(pairs, bucket_cnt, rowBE, csr);

  const int gin_grid = N_NODES / 16;  // 3125
  gin_layer<<<gin_grid, 256, 0, stream>>>(xA, rowBE, csr, Wf + 0 * 16384, gb1 + 0 * D,
                                          Wf + 3 * 16384, gb2 + 0 * D, xB);
  gin_layer<<<gin_grid, 256, 0, stream>>>(xB, rowBE, csr, Wf + 1 * 16384, gb1 + 1 * D,
                                          Wf + 4 * 16384, gb2 + 1 * D, xA);
  gin_layer<<<gin_grid, 256, 0, stream>>>(xA, rowBE, csr, Wf + 2 * 16384, gb1 + 2 * D,
                                          Wf + 5 * 16384, gb2 + 2 * D, xB);

  pred_kernel<<<N_CAND / 128, 256, 0, stream>>>(xB, cand, Wf, ep, pw1, pb1, pw2, pb2, out);
}